// Round 1
// baseline (46.791 us; speedup 1.0000x reference)
//
#include <hip/hip_runtime.h>

// SwirlEffect: out[b,gy,gx,c] = bilinear_warp(x, flow) with
//   flow[...,0] = fv * cos(pi * r[gy]),            r[i] = -1 + i/256
//   flow[...,1] = fv * sin(0.4*w) * log(max(2w,1e-12)), w = sqrt(xr[gx]^2 + xr[gy]^2)
//   xr[j] = j * (f32(10pi)/256) - f32(10pi)
// qy = gy - flow0; qx = gx - flow1; fy=clip(floor(qy),0,510); ay=clip(qy-fy,0,1); etc.
// x: (8,512,512,16) f32; out same. Per-image floats = 2^22; row stride = 2^13; pixel = 2^4.

__device__ __forceinline__ float4 lerp4(float4 a, float4 b, float t) {
    float4 r;
    r.x = a.x + t * (b.x - a.x);
    r.y = a.y + t * (b.y - a.y);
    r.z = a.z + t * (b.z - a.z);
    r.w = a.w + t * (b.w - a.w);
    return r;
}

__global__ __launch_bounds__(256)
void swirl_warp_kernel(const float* __restrict__ x,
                       const float* __restrict__ frame,
                       float* __restrict__ out) {
    __shared__ int   s_off[64];
    __shared__ float s_ay[64];
    __shared__ float s_ax[64];

    const int tid = threadIdx.x;
    const int blk = blockIdx.x;            // 0..4095, 64 pixels per block

    if (tid < 64) {
        const int p = (blk << 6) + tid;    // global pixel index (gy*512+gx)
        const int i = p >> 9;              // gy
        const int j = p & 511;             // gx
        const float fv = frame[0];

        // y-flow: fv * cos(pi * r[i])
        const float ri  = -1.0f + (float)i * (1.0f / 256.0f);        // exact
        const float yfl = fv * cosf(ri * 3.14159274101257324e0f);    // f32(pi)

        // x-flow: fv * sin(0.4 w) * log(max(2w, 1e-12))
        const float V    = 31.4159259796142578125f;                  // f32(10*pi)
        const float step = V * (1.0f / 256.0f);                      // exact scaling
        const float xj   = (float)j * step - V;
        const float xi   = (float)i * step - V;
        const float wave = sqrtf(xj * xj + xi * xi);
        const float xfl  = fv * (sinf(0.4f * wave) * logf(fmaxf(2.0f * wave, 1e-12f)));

        const float qy = (float)i - yfl;
        const float qx = (float)j - xfl;
        const float fy = fminf(fmaxf(floorf(qy), 0.0f), 510.0f);
        const float fx = fminf(fmaxf(floorf(qx), 0.0f), 510.0f);

        s_ay[tid]  = fminf(fmaxf(qy - fy, 0.0f), 1.0f);
        s_ax[tid]  = fminf(fmaxf(qx - fx, 0.0f), 1.0f);
        s_off[tid] = ((int)fy << 13) + ((int)fx << 4);               // float offset of TL pixel
    }
    __syncthreads();

    const int pl  = tid >> 2;              // local pixel 0..63
    const int ch  = tid & 3;               // float4 chunk 0..3
    const int off = s_off[pl] + (ch << 2);
    const float ay = s_ay[pl];
    const float ax = s_ax[pl];
    const int p     = (blk << 6) + pl;
    const int obase = (p << 4) + (ch << 2);

    #pragma unroll
    for (int b = 0; b < 8; ++b) {
        const float* img = x + ((size_t)b << 22);
        const float4 tl = *reinterpret_cast<const float4*>(img + off);
        const float4 tr = *reinterpret_cast<const float4*>(img + off + 16);
        const float4 bl = *reinterpret_cast<const float4*>(img + off + (1 << 13));
        const float4 br = *reinterpret_cast<const float4*>(img + off + (1 << 13) + 16);

        const float4 top = lerp4(tl, tr, ax);
        const float4 bot = lerp4(bl, br, ax);
        const float4 o   = lerp4(top, bot, ay);

        *reinterpret_cast<float4*>(out + ((size_t)b << 22) + obase) = o;
    }
}

extern "C" void kernel_launch(void* const* d_in, const int* in_sizes, int n_in,
                              void* d_out, int out_size, void* d_ws, size_t ws_size,
                              hipStream_t stream) {
    const float* x  = (const float*)d_in[0];
    const float* fv = (const float*)d_in[1];
    float* out      = (float*)d_out;

    // 512*512 pixels / 64 pixels-per-block = 4096 blocks
    swirl_warp_kernel<<<4096, 256, 0, stream>>>(x, fv, out);
}